// Round 1
// baseline (321.917 us; speedup 1.0000x reference)
//
#include <hip/hip_runtime.h>

#define B_TOTAL 50000
#define NSAMP   16
#define FDIM    256
#define KDIM    512   // 2*FDIM
#define EDIM    256
#define NB      64    // batch columns per block

typedef __attribute__((ext_vector_type(4))) float float4v;
typedef __attribute__((ext_vector_type(4))) short short4v;
typedef __attribute__((ext_vector_type(8))) short short8v;

__device__ __forceinline__ unsigned short f2bf(float f) {
  unsigned int u = __builtin_bit_cast(unsigned int, f);
  u += 0x7FFFu + ((u >> 16) & 1u);   // round-to-nearest-even
  return (unsigned short)(u >> 16);
}

__device__ __forceinline__ short4v pack4(float4v v) {
  short4v r;
  r[0] = (short)f2bf(v[0]);
  r[1] = (short)f2bf(v[1]);
  r[2] = (short)f2bf(v[2]);
  r[3] = (short)f2bf(v[3]);
  return r;
}

__global__ __launch_bounds__(256, 1) void encoder_fused(
    const int* __restrict__ nodes,
    const int* __restrict__ neigh,
    const float* __restrict__ features,
    const float* __restrict__ weight,
    float* __restrict__ out) {
  // combined tile: [NB rows][512 k] bf16, XOR-swizzled -> 64KB
  __shared__ alignas(16) unsigned char lds_cmb[NB * KDIM * 2];
  // W chunk: [256 e][128 k] bf16, XOR-swizzled -> 64KB
  __shared__ alignas(16) unsigned char lds_w[EDIM * 128 * 2];

  const int tid = threadIdx.x;
  const int l   = tid & 63;   // lane
  const int w   = tid >> 6;   // wave 0..3
  const int b0  = blockIdx.x * NB;

  // ---------- Phase 1: gather + mean -> bf16 combined tile ----------
  // wave w handles rows w*16 .. w*16+15; one wave loads one 1KB feature row
  // per instruction (float4/lane, fully coalesced).
  for (int rr = 0; rr < 16; ++rr) {
    const int r  = w * 16 + rr;
    const int rb = b0 + r;
    unsigned char* rowp = lds_cmb + r * (KDIM * 2);
    const unsigned int sw = (unsigned)(r & 7) << 4;
    if (rb < B_TOTAL) {
      const int node = nodes[rb];
      float4v selfv = *(const float4v*)(features + (size_t)node * FDIM + l * 4);
      float4v accv = {0.f, 0.f, 0.f, 0.f};
      #pragma unroll
      for (int s = 0; s < NSAMP; ++s) {
        const int ni = neigh[rb * NSAMP + s];
        accv += *(const float4v*)(features + (size_t)ni * FDIM + l * 4);
      }
      accv *= 0.0625f;
      // self -> k = l*4 .. l*4+3 ; mean -> k = 256 + l*4 ..
      *(short4v*)(rowp + (((unsigned)(l * 8)) ^ sw))       = pack4(selfv);
      *(short4v*)(rowp + (((unsigned)(512 + l * 8)) ^ sw)) = pack4(accv);
    } else {
      short4v z = {0, 0, 0, 0};
      *(short4v*)(rowp + (((unsigned)(l * 8)) ^ sw))       = z;
      *(short4v*)(rowp + (((unsigned)(512 + l * 8)) ^ sw)) = z;
    }
  }

  // ---------- Phase 2: GEMM  out[e,b] = sum_k W[e,k]*X[b,k] ----------
  const int lr = l & 15;   // 16-index (m for A, n for B)
  const int g  = l >> 4;   // k-group
  float4v acc[4][4];
  #pragma unroll
  for (int mi = 0; mi < 4; ++mi)
    #pragma unroll
    for (int ni = 0; ni < 4; ++ni)
      acc[mi][ni] = (float4v){0.f, 0.f, 0.f, 0.f};

  for (int kc = 0; kc < 4; ++kc) {
    __syncthreads();           // prev compute done (and phase-1 done at kc=0)
    const int k0 = kc * 128;
    // cooperative stage of W[0:256][k0:k0+128] as bf16, coalesced f32 reads
    for (int i = tid; i < EDIM * 32; i += 256) {
      const int e  = i >> 5;
      const int kq = i & 31;
      float4v wv = *(const float4v*)(weight + (size_t)e * KDIM + k0 + kq * 4);
      *(short4v*)(lds_w + e * 256 + (((unsigned)(kq * 8)) ^ ((unsigned)(e & 7) << 4))) = pack4(wv);
    }
    __syncthreads();
    #pragma unroll
    for (int ks = 0; ks < 4; ++ks) {
      const int ko = ks * 32;
      short8v afr[4], bfr[4];
      #pragma unroll
      for (int mi = 0; mi < 4; ++mi) {
        const int e = w * 64 + mi * 16 + lr;
        const unsigned int sw = (unsigned)(e & 7) << 4;
        const unsigned char* base = lds_w + e * 256;
        short4v lo = *(const short4v*)(base + (((unsigned)((ko + 4 * g) * 2)) ^ sw));
        short4v hi = *(const short4v*)(base + (((unsigned)((ko + 16 + 4 * g) * 2)) ^ sw));
        afr[mi] = __builtin_shufflevector(lo, hi, 0, 1, 2, 3, 4, 5, 6, 7);
      }
      #pragma unroll
      for (int ni = 0; ni < 4; ++ni) {
        const int rrow = ni * 16 + lr;
        const unsigned int sw = (unsigned)(rrow & 7) << 4;
        const unsigned char* base = lds_cmb + rrow * (KDIM * 2);
        const int kk = k0 + ko;
        short4v lo = *(const short4v*)(base + (((unsigned)((kk + 4 * g) * 2)) ^ sw));
        short4v hi = *(const short4v*)(base + (((unsigned)((kk + 16 + 4 * g) * 2)) ^ sw));
        bfr[ni] = __builtin_shufflevector(lo, hi, 0, 1, 2, 3, 4, 5, 6, 7);
      }
      #pragma unroll
      for (int mi = 0; mi < 4; ++mi)
        #pragma unroll
        for (int ni = 0; ni < 4; ++ni)
          acc[mi][ni] = __builtin_amdgcn_mfma_f32_16x16x32_bf16(afr[mi], bfr[ni], acc[mi][ni], 0, 0, 0);
    }
  }

  // ---------- Epilogue: ReLU + store ----------
  #pragma unroll
  for (int ni = 0; ni < 4; ++ni) {
    const int b = b0 + ni * 16 + lr;
    if (b >= B_TOTAL) continue;
    #pragma unroll
    for (int mi = 0; mi < 4; ++mi) {
      const int e = w * 64 + mi * 16 + g * 4;
      #pragma unroll
      for (int q = 0; q < 4; ++q) {
        float v = acc[mi][ni][q];
        out[(size_t)(e + q) * B_TOTAL + b] = v > 0.f ? v : 0.f;
      }
    }
  }
}

extern "C" void kernel_launch(void* const* d_in, const int* in_sizes, int n_in,
                              void* d_out, int out_size, void* d_ws, size_t ws_size,
                              hipStream_t stream) {
  const int*   nodes    = (const int*)d_in[0];
  const int*   neigh    = (const int*)d_in[1];
  const float* features = (const float*)d_in[2];
  const float* weight   = (const float*)d_in[3];
  float*       out      = (float*)d_out;

  const int nblocks = (B_TOTAL + NB - 1) / NB;  // 782
  encoder_fused<<<nblocks, 256, 0, stream>>>(nodes, neigh, features, weight, out);
}

// Round 2
// 208.190 us; speedup vs baseline: 1.5463x; 1.5463x over previous
//
#include <hip/hip_runtime.h>

#define B_TOTAL 50000
#define NSAMP   16
#define FDIM    256
#define KDIM    512   // 2*FDIM
#define EDIM    256
#define NBT     128   // batch tile for GEMM kernel
#define B_PAD   50048 // B_TOTAL rounded up to NBT

typedef __attribute__((ext_vector_type(4))) float float4v;
typedef __attribute__((ext_vector_type(4))) short short4v;
typedef __attribute__((ext_vector_type(8))) short short8v;

__device__ __forceinline__ unsigned short f2bf(float f) {
  unsigned int u = __builtin_bit_cast(unsigned int, f);
  u += 0x7FFFu + ((u >> 16) & 1u);   // round-to-nearest-even
  return (unsigned short)(u >> 16);
}

__device__ __forceinline__ short4v pack4(float4v v) {
  short4v r;
  r[0] = (short)f2bf(v[0]);
  r[1] = (short)f2bf(v[1]);
  r[2] = (short)f2bf(v[2]);
  r[3] = (short)f2bf(v[3]);
  return r;
}

// ---------------------------------------------------------------------------
// Kernel 1: gather + mean -> bf16 combined matrix X [B_PAD][512] in ws.
// No LDS, one wave per row, 17 independent float4 loads in flight per wave.
// ---------------------------------------------------------------------------
__global__ __launch_bounds__(256, 4) void gather_mean(
    const int* __restrict__ nodes,
    const int* __restrict__ neigh,
    const float* __restrict__ features,
    unsigned short* __restrict__ xout) {
  const int l = threadIdx.x & 63;
  const int w = threadIdx.x >> 6;
  const int row = __builtin_amdgcn_readfirstlane(blockIdx.x * 4 + w);
  if (row >= B_PAD) return;

  unsigned short* rowp = xout + (size_t)row * KDIM;
  if (row < B_TOTAL) {
    const int node = nodes[row];
    float4v selfv = *(const float4v*)(features + (size_t)node * FDIM + l * 4);
    float4v accv = {0.f, 0.f, 0.f, 0.f};
    #pragma unroll
    for (int s = 0; s < NSAMP; ++s) {
      const int ni = neigh[row * NSAMP + s];
      accv += *(const float4v*)(features + (size_t)ni * FDIM + l * 4);
    }
    accv *= 0.0625f;
    *(short4v*)(rowp + l * 4)        = pack4(selfv);
    *(short4v*)(rowp + FDIM + l * 4) = pack4(accv);
  } else {
    short4v z = {0, 0, 0, 0};
    *(short4v*)(rowp + l * 4)        = z;
    *(short4v*)(rowp + FDIM + l * 4) = z;
  }
}

// ---------------------------------------------------------------------------
// Kernel 2: out[e,b] = relu( sum_k W[e,k] * X[b,k] ), MFMA bf16.
// Tile: 256 E x 128 batch, 8 waves (4 E-quarters x 2 batch-halves), K chunked
// by 128. LDS = 64KB (W chunk) + 32KB (X chunk) = 96KB.
// ---------------------------------------------------------------------------
__global__ __launch_bounds__(512) void gemm_relu(
    const unsigned short* __restrict__ xin,
    const float* __restrict__ weight,
    float* __restrict__ out) {
  __shared__ alignas(16) unsigned char lds_w[EDIM * 128 * 2];  // 64KB
  __shared__ alignas(16) unsigned char lds_x[NBT * 128 * 2];   // 32KB

  const int tid = threadIdx.x;
  const int l   = tid & 63;
  const int w   = tid >> 6;     // 0..7
  const int we  = w & 3;        // E quarter (64 rows)
  const int wb  = w >> 2;       // batch half (64 cols)
  const int lr  = l & 15;
  const int g   = l >> 4;
  const int b0  = blockIdx.x * NBT;

  float4v acc[4][4];
  #pragma unroll
  for (int mi = 0; mi < 4; ++mi)
    #pragma unroll
    for (int ni = 0; ni < 4; ++ni)
      acc[mi][ni] = (float4v){0.f, 0.f, 0.f, 0.f};

  for (int kc = 0; kc < 4; ++kc) {
    __syncthreads();
    const int k0 = kc * 128;
    // stage W[0:256][k0:k0+128] f32 -> bf16 swizzled
    for (int i = tid; i < EDIM * 32; i += 512) {
      const int e  = i >> 5;
      const int kq = i & 31;
      float4v wv = *(const float4v*)(weight + (size_t)e * KDIM + k0 + kq * 4);
      *(short4v*)(lds_w + e * 256 + (((unsigned)(kq * 8)) ^ ((unsigned)(e & 7) << 4))) = pack4(wv);
    }
    // stage X[b0:b0+128][k0:k0+128] bf16 -> swizzled (16B chunks)
    for (int i = tid; i < NBT * 16; i += 512) {
      const int r = i >> 4;
      const int j = i & 15;
      short8v xv = *(const short8v*)(xin + (size_t)(b0 + r) * KDIM + k0 + j * 8);
      *(short8v*)(lds_x + r * 256 + (((unsigned)(j * 16)) ^ ((unsigned)(r & 7) << 4))) = xv;
    }
    __syncthreads();
    #pragma unroll
    for (int ks = 0; ks < 4; ++ks) {
      const int ko = ks * 32;
      short8v afr[4], bfr[4];
      #pragma unroll
      for (int mi = 0; mi < 4; ++mi) {
        const int e = we * 64 + mi * 16 + lr;
        const unsigned int sw = (unsigned)(e & 7) << 4;
        const unsigned char* base = lds_w + e * 256;
        short4v lo = *(const short4v*)(base + (((unsigned)((ko + 4 * g) * 2)) ^ sw));
        short4v hi = *(const short4v*)(base + (((unsigned)((ko + 16 + 4 * g) * 2)) ^ sw));
        afr[mi] = __builtin_shufflevector(lo, hi, 0, 1, 2, 3, 4, 5, 6, 7);
      }
      #pragma unroll
      for (int ni = 0; ni < 4; ++ni) {
        const int r = wb * 64 + ni * 16 + lr;
        const unsigned int sw = (unsigned)(r & 7) << 4;
        const unsigned char* base = lds_x + r * 256;
        short4v lo = *(const short4v*)(base + (((unsigned)((ko + 4 * g) * 2)) ^ sw));
        short4v hi = *(const short4v*)(base + (((unsigned)((ko + 16 + 4 * g) * 2)) ^ sw));
        bfr[ni] = __builtin_shufflevector(lo, hi, 0, 1, 2, 3, 4, 5, 6, 7);
      }
      #pragma unroll
      for (int mi = 0; mi < 4; ++mi)
        #pragma unroll
        for (int ni = 0; ni < 4; ++ni)
          acc[mi][ni] = __builtin_amdgcn_mfma_f32_16x16x32_bf16(afr[mi], bfr[ni], acc[mi][ni], 0, 0, 0);
    }
  }

  #pragma unroll
  for (int ni = 0; ni < 4; ++ni) {
    const int b = b0 + wb * 64 + ni * 16 + lr;
    if (b >= B_TOTAL) continue;
    #pragma unroll
    for (int mi = 0; mi < 4; ++mi) {
      const int e = we * 64 + mi * 16 + g * 4;
      #pragma unroll
      for (int q = 0; q < 4; ++q) {
        float v = acc[mi][ni][q];
        out[(size_t)(e + q) * B_TOTAL + b] = v > 0.f ? v : 0.f;
      }
    }
  }
}

// ---------------------------------------------------------------------------
// Fallback: round-1 fused kernel (used only if ws is too small).
// ---------------------------------------------------------------------------
__global__ __launch_bounds__(256, 1) void encoder_fused(
    const int* __restrict__ nodes,
    const int* __restrict__ neigh,
    const float* __restrict__ features,
    const float* __restrict__ weight,
    float* __restrict__ out) {
  __shared__ alignas(16) unsigned char lds_cmb[64 * KDIM * 2];
  __shared__ alignas(16) unsigned char lds_w[EDIM * 128 * 2];

  const int tid = threadIdx.x;
  const int l   = tid & 63;
  const int w   = tid >> 6;
  const int b0  = blockIdx.x * 64;

  for (int rr = 0; rr < 16; ++rr) {
    const int r  = w * 16 + rr;
    const int rb = b0 + r;
    unsigned char* rowp = lds_cmb + r * (KDIM * 2);
    const unsigned int sw = (unsigned)(r & 7) << 4;
    if (rb < B_TOTAL) {
      const int node = nodes[rb];
      float4v selfv = *(const float4v*)(features + (size_t)node * FDIM + l * 4);
      float4v accv = {0.f, 0.f, 0.f, 0.f};
      #pragma unroll
      for (int s = 0; s < NSAMP; ++s) {
        const int ni = neigh[rb * NSAMP + s];
        accv += *(const float4v*)(features + (size_t)ni * FDIM + l * 4);
      }
      accv *= 0.0625f;
      *(short4v*)(rowp + (((unsigned)(l * 8)) ^ sw))       = pack4(selfv);
      *(short4v*)(rowp + (((unsigned)(512 + l * 8)) ^ sw)) = pack4(accv);
    } else {
      short4v z = {0, 0, 0, 0};
      *(short4v*)(rowp + (((unsigned)(l * 8)) ^ sw))       = z;
      *(short4v*)(rowp + (((unsigned)(512 + l * 8)) ^ sw)) = z;
    }
  }

  const int lr = l & 15;
  const int g  = l >> 4;
  float4v acc[4][4];
  #pragma unroll
  for (int mi = 0; mi < 4; ++mi)
    #pragma unroll
    for (int ni = 0; ni < 4; ++ni)
      acc[mi][ni] = (float4v){0.f, 0.f, 0.f, 0.f};

  for (int kc = 0; kc < 4; ++kc) {
    __syncthreads();
    const int k0 = kc * 128;
    for (int i = tid; i < EDIM * 32; i += 256) {
      const int e  = i >> 5;
      const int kq = i & 31;
      float4v wv = *(const float4v*)(weight + (size_t)e * KDIM + k0 + kq * 4);
      *(short4v*)(lds_w + e * 256 + (((unsigned)(kq * 8)) ^ ((unsigned)(e & 7) << 4))) = pack4(wv);
    }
    __syncthreads();
    #pragma unroll
    for (int ks = 0; ks < 4; ++ks) {
      const int ko = ks * 32;
      short8v afr[4], bfr[4];
      #pragma unroll
      for (int mi = 0; mi < 4; ++mi) {
        const int e = w * 64 + mi * 16 + lr;
        const unsigned int sw = (unsigned)(e & 7) << 4;
        const unsigned char* base = lds_w + e * 256;
        short4v lo = *(const short4v*)(base + (((unsigned)((ko + 4 * g) * 2)) ^ sw));
        short4v hi = *(const short4v*)(base + (((unsigned)((ko + 16 + 4 * g) * 2)) ^ sw));
        afr[mi] = __builtin_shufflevector(lo, hi, 0, 1, 2, 3, 4, 5, 6, 7);
      }
      #pragma unroll
      for (int ni = 0; ni < 4; ++ni) {
        const int rrow = ni * 16 + lr;
        const unsigned int sw = (unsigned)(rrow & 7) << 4;
        const unsigned char* base = lds_cmb + rrow * (KDIM * 2);
        const int kk = k0 + ko;
        short4v lo = *(const short4v*)(base + (((unsigned)((kk + 4 * g) * 2)) ^ sw));
        short4v hi = *(const short4v*)(base + (((unsigned)((kk + 16 + 4 * g) * 2)) ^ sw));
        bfr[ni] = __builtin_shufflevector(lo, hi, 0, 1, 2, 3, 4, 5, 6, 7);
      }
      #pragma unroll
      for (int mi = 0; mi < 4; ++mi)
        #pragma unroll
        for (int ni = 0; ni < 4; ++ni)
          acc[mi][ni] = __builtin_amdgcn_mfma_f32_16x16x32_bf16(afr[mi], bfr[ni], acc[mi][ni], 0, 0, 0);
    }
  }

  #pragma unroll
  for (int ni = 0; ni < 4; ++ni) {
    const int b = b0 + ni * 16 + lr;
    if (b >= B_TOTAL) continue;
    #pragma unroll
    for (int mi = 0; mi < 4; ++mi) {
      const int e = w * 64 + mi * 16 + g * 4;
      #pragma unroll
      for (int q = 0; q < 4; ++q) {
        float v = acc[mi][ni][q];
        out[(size_t)(e + q) * B_TOTAL + b] = v > 0.f ? v : 0.f;
      }
    }
  }
}

extern "C" void kernel_launch(void* const* d_in, const int* in_sizes, int n_in,
                              void* d_out, int out_size, void* d_ws, size_t ws_size,
                              hipStream_t stream) {
  const int*   nodes    = (const int*)d_in[0];
  const int*   neigh    = (const int*)d_in[1];
  const float* features = (const float*)d_in[2];
  const float* weight   = (const float*)d_in[3];
  float*       out      = (float*)d_out;

  const size_t ws_needed = (size_t)B_PAD * KDIM * sizeof(unsigned short);
  if (ws_size >= ws_needed) {
    unsigned short* xmat = (unsigned short*)d_ws;
    gather_mean<<<B_PAD / 4, 256, 0, stream>>>(nodes, neigh, features, xmat);
    gemm_relu<<<B_PAD / NBT, 512, 0, stream>>>(xmat, weight, out);
  } else {
    encoder_fused<<<(B_TOTAL + 63) / 64, 256, 0, stream>>>(nodes, neigh, features, weight, out);
  }
}

// Round 3
// 164.734 us; speedup vs baseline: 1.9542x; 1.2638x over previous
//
#include <hip/hip_runtime.h>

#define B_TOTAL 50000
#define NSAMP   16
#define FDIM    256
#define KDIM    512   // 2*FDIM
#define EDIM    256
#define NBT     64    // batch columns per GEMM block
#define B_PAD   50048 // B_TOTAL rounded to NBT
#define NBLK    (B_PAD / NBT)   // 782

// X image: [blk][kc=4][rloc=64][256B swizzled]  -> 64KB per blk, 50.05MB total
#define XCHUNK  16384            // 64 rows * 256B
#define XBLK    (4 * XCHUNK)     // 65536
// W image: [kc=4][e=256][256B swizzled] -> 256KB, placed after X image in ws
#define WIMG_OFF ((size_t)NBLK * XBLK)

typedef __attribute__((ext_vector_type(4))) float float4v;
typedef __attribute__((ext_vector_type(4))) short short4v;
typedef __attribute__((ext_vector_type(8))) short short8v;

__device__ __forceinline__ unsigned short f2bf(float f) {
  unsigned int u = __builtin_bit_cast(unsigned int, f);
  u += 0x7FFFu + ((u >> 16) & 1u);   // round-to-nearest-even
  return (unsigned short)(u >> 16);
}

__device__ __forceinline__ short4v pack4(float4v v) {
  short4v r;
  r[0] = (short)f2bf(v[0]);
  r[1] = (short)f2bf(v[1]);
  r[2] = (short)f2bf(v[2]);
  r[3] = (short)f2bf(v[3]);
  return r;
}

__device__ __forceinline__ void lds_load16(const void* g, void* l) {
  __builtin_amdgcn_global_load_lds(
      (const __attribute__((address_space(1))) unsigned int*)g,
      (__attribute__((address_space(3))) unsigned int*)l, 16, 0, 0);
}

// ---------------------------------------------------------------------------
// Kernel 0: pack W f32 [256][512] -> bf16 swizzled image in ws.
// ---------------------------------------------------------------------------
__global__ __launch_bounds__(256) void pack_w(
    const float* __restrict__ weight, unsigned char* __restrict__ wimg) {
  const int idx = blockIdx.x * 256 + threadIdx.x;   // 32768 total
  const int e  = idx >> 7;         // 0..255
  const int kq = idx & 127;        // float4 index within row
  const int k  = kq * 4;
  const int kc = k >> 7;
  const int kl = k & 127;
  float4v wv = *(const float4v*)(weight + (size_t)e * KDIM + k);
  *(short4v*)(wimg + kc * 65536 + e * 256 +
              (((unsigned)(kl * 2)) ^ ((unsigned)(e & 7) << 4))) = pack4(wv);
}

// ---------------------------------------------------------------------------
// Kernel 1: gather + mean -> bf16 X image (tiled + swizzled) in ws.
// One wave per row; 17 loads into named regs -> all in flight at once.
// ---------------------------------------------------------------------------
__global__ __launch_bounds__(256, 4) void gather_mean(
    const int* __restrict__ nodes,
    const int* __restrict__ neigh,
    const float* __restrict__ features,
    unsigned char* __restrict__ ximg) {
  const int l = threadIdx.x & 63;
  const int w = threadIdx.x >> 6;
  const int row = __builtin_amdgcn_readfirstlane(blockIdx.x * 4 + w);
  if (row >= B_PAD) return;

  const int blk  = row >> 6;
  const int rloc = row & 63;
  unsigned char* base = ximg + (size_t)blk * XBLK + rloc * 256;
  const unsigned int sw  = (unsigned)(rloc & 7) << 4;
  const unsigned int off = (((unsigned)(l * 8)) & 255u) ^ sw;  // byte within 256B row
  const int kcs = l >> 5;  // self chunk 0/1 ; mean chunk 2/3

  if (row < B_TOTAL) {
    const int node = nodes[row];
    const size_t fo = (size_t)l * 4;
    float4v vs = *(const float4v*)(features + (size_t)node * FDIM + fo);
    float4v v0  = *(const float4v*)(features + (size_t)neigh[row * NSAMP +  0] * FDIM + fo);
    float4v v1  = *(const float4v*)(features + (size_t)neigh[row * NSAMP +  1] * FDIM + fo);
    float4v v2  = *(const float4v*)(features + (size_t)neigh[row * NSAMP +  2] * FDIM + fo);
    float4v v3  = *(const float4v*)(features + (size_t)neigh[row * NSAMP +  3] * FDIM + fo);
    float4v v4  = *(const float4v*)(features + (size_t)neigh[row * NSAMP +  4] * FDIM + fo);
    float4v v5  = *(const float4v*)(features + (size_t)neigh[row * NSAMP +  5] * FDIM + fo);
    float4v v6  = *(const float4v*)(features + (size_t)neigh[row * NSAMP +  6] * FDIM + fo);
    float4v v7  = *(const float4v*)(features + (size_t)neigh[row * NSAMP +  7] * FDIM + fo);
    float4v v8  = *(const float4v*)(features + (size_t)neigh[row * NSAMP +  8] * FDIM + fo);
    float4v v9  = *(const float4v*)(features + (size_t)neigh[row * NSAMP +  9] * FDIM + fo);
    float4v v10 = *(const float4v*)(features + (size_t)neigh[row * NSAMP + 10] * FDIM + fo);
    float4v v11 = *(const float4v*)(features + (size_t)neigh[row * NSAMP + 11] * FDIM + fo);
    float4v v12 = *(const float4v*)(features + (size_t)neigh[row * NSAMP + 12] * FDIM + fo);
    float4v v13 = *(const float4v*)(features + (size_t)neigh[row * NSAMP + 13] * FDIM + fo);
    float4v v14 = *(const float4v*)(features + (size_t)neigh[row * NSAMP + 14] * FDIM + fo);
    float4v v15 = *(const float4v*)(features + (size_t)neigh[row * NSAMP + 15] * FDIM + fo);
    // tree sum (keeps loads independent)
    v0 += v1;  v2 += v3;  v4 += v5;  v6 += v7;
    v8 += v9;  v10 += v11; v12 += v13; v14 += v15;
    v0 += v2;  v4 += v6;  v8 += v10; v12 += v14;
    v0 += v4;  v8 += v12;
    v0 += v8;
    v0 *= 0.0625f;
    *(short4v*)(base + kcs * XCHUNK + off)       = pack4(vs);
    *(short4v*)(base + (2 + kcs) * XCHUNK + off) = pack4(v0);
  } else {
    short4v z = {0, 0, 0, 0};
    *(short4v*)(base + kcs * XCHUNK + off)       = z;
    *(short4v*)(base + (2 + kcs) * XCHUNK + off) = z;
  }
}

// ---------------------------------------------------------------------------
// Kernel 2: out[e,b] = relu( sum_k W[e,k] * X[b,k] ), MFMA bf16.
// 256 threads, 4 waves (one 64-row E quarter each), NBT=64 batch cols.
// Staging = pure global_load_lds (images pre-swizzled). LDS 80KB -> 2 blk/CU.
// ---------------------------------------------------------------------------
__global__ __launch_bounds__(256) void gemm_relu(
    const unsigned char* __restrict__ ximg,
    const unsigned char* __restrict__ wimg,
    float* __restrict__ out) {
  __shared__ alignas(16) unsigned char lds_w[EDIM * 256];   // 64KB
  __shared__ alignas(16) unsigned char lds_x[NBT * 256];    // 16KB

  const int tid = threadIdx.x;
  const int l   = tid & 63;
  const int w   = tid >> 6;     // 0..3 : E quarter
  const int lr  = l & 15;
  const int g   = l >> 4;
  const int b0  = blockIdx.x * NBT;
  const unsigned char* xsrc = ximg + (size_t)blockIdx.x * XBLK;

  float4v acc[4][4];
  #pragma unroll
  for (int mi = 0; mi < 4; ++mi)
    #pragma unroll
    for (int ni = 0; ni < 4; ++ni)
      acc[mi][ni] = (float4v){0.f, 0.f, 0.f, 0.f};

  for (int kc = 0; kc < 4; ++kc) {
    __syncthreads();
    // stage W chunk: 64KB, 16 x (256 thr * 16B)
    {
      const unsigned char* ws_ = wimg + kc * 65536;
      #pragma unroll
      for (int i = 0; i < 16; ++i)
        lds_load16(ws_ + i * 4096 + tid * 16, lds_w + i * 4096 + (w << 10));
      // stage X chunk: 16KB, 4 x (256 thr * 16B)
      const unsigned char* xs_ = xsrc + kc * XCHUNK;
      #pragma unroll
      for (int i = 0; i < 4; ++i)
        lds_load16(xs_ + i * 4096 + tid * 16, lds_x + i * 4096 + (w << 10));
    }
    __syncthreads();
    #pragma unroll
    for (int ks = 0; ks < 4; ++ks) {
      const int ko = ks * 32;
      short8v afr[4], bfr[4];
      #pragma unroll
      for (int mi = 0; mi < 4; ++mi) {
        const int e = w * 64 + mi * 16 + lr;
        const unsigned int sw = (unsigned)(e & 7) << 4;
        const unsigned char* base = lds_w + e * 256;
        short4v lo = *(const short4v*)(base + (((unsigned)((ko + 4 * g) * 2)) ^ sw));
        short4v hi = *(const short4v*)(base + (((unsigned)((ko + 16 + 4 * g) * 2)) ^ sw));
        afr[mi] = __builtin_shufflevector(lo, hi, 0, 1, 2, 3, 4, 5, 6, 7);
      }
      #pragma unroll
      for (int ni = 0; ni < 4; ++ni) {
        const int r = ni * 16 + lr;
        const unsigned int sw = (unsigned)(r & 7) << 4;
        const unsigned char* base = lds_x + r * 256;
        short4v lo = *(const short4v*)(base + (((unsigned)((ko + 4 * g) * 2)) ^ sw));
        short4v hi = *(const short4v*)(base + (((unsigned)((ko + 16 + 4 * g) * 2)) ^ sw));
        bfr[ni] = __builtin_shufflevector(lo, hi, 0, 1, 2, 3, 4, 5, 6, 7);
      }
      #pragma unroll
      for (int mi = 0; mi < 4; ++mi)
        #pragma unroll
        for (int ni = 0; ni < 4; ++ni)
          acc[mi][ni] = __builtin_amdgcn_mfma_f32_16x16x32_bf16(afr[mi], bfr[ni], acc[mi][ni], 0, 0, 0);
    }
  }

  #pragma unroll
  for (int ni = 0; ni < 4; ++ni) {
    const int b = b0 + ni * 16 + lr;
    if (b >= B_TOTAL) continue;
    #pragma unroll
    for (int mi = 0; mi < 4; ++mi) {
      const int e = w * 64 + mi * 16 + g * 4;
      #pragma unroll
      for (int q = 0; q < 4; ++q) {
        float v = acc[mi][ni][q];
        out[(size_t)(e + q) * B_TOTAL + b] = v > 0.f ? v : 0.f;
      }
    }
  }
}

// ---------------------------------------------------------------------------
// Fallback (ws too small): round-1 fused kernel, known-correct.
// ---------------------------------------------------------------------------
__global__ __launch_bounds__(256, 1) void encoder_fused(
    const int* __restrict__ nodes,
    const int* __restrict__ neigh,
    const float* __restrict__ features,
    const float* __restrict__ weight,
    float* __restrict__ out) {
  __shared__ alignas(16) unsigned char lds_cmb[64 * KDIM * 2];
  __shared__ alignas(16) unsigned char lds_w[EDIM * 128 * 2];

  const int tid = threadIdx.x;
  const int l   = tid & 63;
  const int w   = tid >> 6;
  const int b0  = blockIdx.x * 64;

  for (int rr = 0; rr < 16; ++rr) {
    const int r  = w * 16 + rr;
    const int rb = b0 + r;
    unsigned char* rowp = lds_cmb + r * (KDIM * 2);
    const unsigned int sw = (unsigned)(r & 7) << 4;
    if (rb < B_TOTAL) {
      const int node = nodes[rb];
      float4v selfv = *(const float4v*)(features + (size_t)node * FDIM + l * 4);
      float4v accv = {0.f, 0.f, 0.f, 0.f};
      #pragma unroll
      for (int s = 0; s < NSAMP; ++s) {
        const int ni = neigh[rb * NSAMP + s];
        accv += *(const float4v*)(features + (size_t)ni * FDIM + l * 4);
      }
      accv *= 0.0625f;
      *(short4v*)(rowp + (((unsigned)(l * 8)) ^ sw))       = pack4(selfv);
      *(short4v*)(rowp + (((unsigned)(512 + l * 8)) ^ sw)) = pack4(accv);
    } else {
      short4v z = {0, 0, 0, 0};
      *(short4v*)(rowp + (((unsigned)(l * 8)) ^ sw))       = z;
      *(short4v*)(rowp + (((unsigned)(512 + l * 8)) ^ sw)) = z;
    }
  }

  const int lr = l & 15;
  const int g  = l >> 4;
  float4v acc[4][4];
  #pragma unroll
  for (int mi = 0; mi < 4; ++mi)
    #pragma unroll
    for (int ni = 0; ni < 4; ++ni)
      acc[mi][ni] = (float4v){0.f, 0.f, 0.f, 0.f};

  for (int kc = 0; kc < 4; ++kc) {
    __syncthreads();
    const int k0 = kc * 128;
    for (int i = tid; i < EDIM * 32; i += 256) {
      const int e  = i >> 5;
      const int kq = i & 31;
      float4v wv = *(const float4v*)(weight + (size_t)e * KDIM + k0 + kq * 4);
      *(short4v*)(lds_w + e * 256 + (((unsigned)(kq * 8)) ^ ((unsigned)(e & 7) << 4))) = pack4(wv);
    }
    __syncthreads();
    #pragma unroll
    for (int ks = 0; ks < 4; ++ks) {
      const int ko = ks * 32;
      short8v afr[4], bfr[4];
      #pragma unroll
      for (int mi = 0; mi < 4; ++mi) {
        const int e = w * 64 + mi * 16 + lr;
        const unsigned int sw = (unsigned)(e & 7) << 4;
        const unsigned char* base = lds_w + e * 256;
        short4v lo = *(const short4v*)(base + (((unsigned)((ko + 4 * g) * 2)) ^ sw));
        short4v hi = *(const short4v*)(base + (((unsigned)((ko + 16 + 4 * g) * 2)) ^ sw));
        afr[mi] = __builtin_shufflevector(lo, hi, 0, 1, 2, 3, 4, 5, 6, 7);
      }
      #pragma unroll
      for (int ni = 0; ni < 4; ++ni) {
        const int rrow = ni * 16 + lr;
        const unsigned int sw = (unsigned)(rrow & 7) << 4;
        const unsigned char* base = lds_cmb + rrow * (KDIM * 2);
        const int kk = k0 + ko;
        short4v lo = *(const short4v*)(base + (((unsigned)((kk + 4 * g) * 2)) ^ sw));
        short4v hi = *(const short4v*)(base + (((unsigned)((kk + 16 + 4 * g) * 2)) ^ sw));
        bfr[ni] = __builtin_shufflevector(lo, hi, 0, 1, 2, 3, 4, 5, 6, 7);
      }
      #pragma unroll
      for (int mi = 0; mi < 4; ++mi)
        #pragma unroll
        for (int ni = 0; ni < 4; ++ni)
          acc[mi][ni] = __builtin_amdgcn_mfma_f32_16x16x32_bf16(afr[mi], bfr[ni], acc[mi][ni], 0, 0, 0);
    }
  }

  #pragma unroll
  for (int ni = 0; ni < 4; ++ni) {
    const int b = b0 + ni * 16 + lr;
    if (b >= B_TOTAL) continue;
    #pragma unroll
    for (int mi = 0; mi < 4; ++mi) {
      const int e = w * 64 + mi * 16 + g * 4;
      #pragma unroll
      for (int q = 0; q < 4; ++q) {
        float v = acc[mi][ni][q];
        out[(size_t)(e + q) * B_TOTAL + b] = v > 0.f ? v : 0.f;
      }
    }
  }
}

extern "C" void kernel_launch(void* const* d_in, const int* in_sizes, int n_in,
                              void* d_out, int out_size, void* d_ws, size_t ws_size,
                              hipStream_t stream) {
  const int*   nodes    = (const int*)d_in[0];
  const int*   neigh    = (const int*)d_in[1];
  const float* features = (const float*)d_in[2];
  const float* weight   = (const float*)d_in[3];
  float*       out      = (float*)d_out;

  const size_t ws_needed = WIMG_OFF + 4 * 65536;  // X image + W image
  if (ws_size >= ws_needed) {
    unsigned char* ximg = (unsigned char*)d_ws;
    unsigned char* wimg = (unsigned char*)d_ws + WIMG_OFF;
    pack_w<<<128, 256, 0, stream>>>(weight, wimg);
    gather_mean<<<B_PAD / 4, 256, 0, stream>>>(nodes, neigh, features, ximg);
    gemm_relu<<<NBLK, 256, 0, stream>>>(ximg, wimg, out);
  } else {
    encoder_fused<<<(B_TOTAL + 63) / 64, 256, 0, stream>>>(nodes, neigh, features, weight, out);
  }
}

// Round 4
// 123.004 us; speedup vs baseline: 2.6171x; 1.3393x over previous
//
#include <hip/hip_runtime.h>

#define N_NODES 100000
#define B_TOTAL 50000
#define NSAMP   16
#define FDIM    256
#define KDIM    512   // 2*FDIM
#define EDIM    256
#define NBT     64    // batch columns per GEMM block
#define B_PAD   50048 // B_TOTAL rounded to NBT
#define NBLK    (B_PAD / NBT)   // 782

// X image: [blk][kc=4][rloc=64][256B swizzled]  -> 64KB per blk, 50.05MB total
#define XCHUNK  16384            // 64 rows * 256B
#define XBLK    (4 * XCHUNK)     // 65536
// W image: [kc=4][e=256][256B swizzled] -> 256KB, after X image in ws
#define WIMG_OFF ((size_t)NBLK * XBLK)
#define WIMG_SZ  (4 * 65536)
// bf16 feature image after W image
#define FB_OFF   (WIMG_OFF + WIMG_SZ)
#define FB_SZ    ((size_t)N_NODES * FDIM * 2)

typedef __attribute__((ext_vector_type(4))) float float4v;
typedef __attribute__((ext_vector_type(4))) short short4v;
typedef __attribute__((ext_vector_type(8))) short short8v;
typedef __attribute__((ext_vector_type(2))) unsigned int uint2v;

__device__ __forceinline__ unsigned short f2bf(float f) {
  unsigned int u = __builtin_bit_cast(unsigned int, f);
  u += 0x7FFFu + ((u >> 16) & 1u);   // round-to-nearest-even
  return (unsigned short)(u >> 16);
}

__device__ __forceinline__ short4v pack4(float4v v) {
  short4v r;
  r[0] = (short)f2bf(v[0]);
  r[1] = (short)f2bf(v[1]);
  r[2] = (short)f2bf(v[2]);
  r[3] = (short)f2bf(v[3]);
  return r;
}

__device__ __forceinline__ float4v bf4_to_f32(uint2v u) {
  float4v r;
  r[0] = __builtin_bit_cast(float, u[0] << 16);
  r[1] = __builtin_bit_cast(float, u[0] & 0xffff0000u);
  r[2] = __builtin_bit_cast(float, u[1] << 16);
  r[3] = __builtin_bit_cast(float, u[1] & 0xffff0000u);
  return r;
}

// Inline-asm 8B load: compiler cannot serialize these; we wait manually.
__device__ __forceinline__ uint2v ld8(const void* p) {
  uint2v r;
  asm volatile("global_load_dwordx2 %0, %1, off" : "=v"(r) : "v"(p) : "memory");
  return r;
}

__device__ __forceinline__ void lds_load16(const void* g, void* l) {
  __builtin_amdgcn_global_load_lds(
      (const __attribute__((address_space(1))) unsigned int*)g,
      (__attribute__((address_space(3))) unsigned int*)l, 16, 0, 0);
}

// ---------------------------------------------------------------------------
// Kernel A: features f32 -> bf16 linear image (one-time, 102R + 51W MB).
// ---------------------------------------------------------------------------
__global__ __launch_bounds__(256) void feat_pack(
    const float* __restrict__ f, unsigned short* __restrict__ o) {
  const size_t i = ((size_t)blockIdx.x * 256 + threadIdx.x) * 8;
  if (i >= (size_t)N_NODES * FDIM) return;
  float4v a = *(const float4v*)(f + i);
  float4v b = *(const float4v*)(f + i + 4);
  short4v ra = pack4(a), rb = pack4(b);
  short8v r;
  r[0]=ra[0]; r[1]=ra[1]; r[2]=ra[2]; r[3]=ra[3];
  r[4]=rb[0]; r[5]=rb[1]; r[6]=rb[2]; r[7]=rb[3];
  *(short8v*)(o + i) = r;
}

// ---------------------------------------------------------------------------
// Kernel 0: pack W f32 [256][512] -> bf16 swizzled image in ws.
// ---------------------------------------------------------------------------
__global__ __launch_bounds__(256) void pack_w(
    const float* __restrict__ weight, unsigned char* __restrict__ wimg) {
  const int idx = blockIdx.x * 256 + threadIdx.x;   // 32768 total
  const int e  = idx >> 7;
  const int kq = idx & 127;
  const int k  = kq * 4;
  const int kc = k >> 7;
  const int kl = k & 127;
  float4v wv = *(const float4v*)(weight + (size_t)e * KDIM + k);
  *(short4v*)(wimg + kc * 65536 + e * 256 +
              (((unsigned)(kl * 2)) ^ ((unsigned)(e & 7) << 4))) = pack4(wv);
}

// ---------------------------------------------------------------------------
// Kernel 1: gather + mean from bf16 features -> X image. One wave per row;
// 17 asm loads all in flight, single vmcnt(0).
// ---------------------------------------------------------------------------
__global__ __launch_bounds__(256, 4) void gather_mean_bf16(
    const int* __restrict__ nodes,
    const int* __restrict__ neigh,
    const unsigned short* __restrict__ fb,
    unsigned char* __restrict__ ximg) {
  const int l = threadIdx.x & 63;
  const int w = threadIdx.x >> 6;
  const int row = __builtin_amdgcn_readfirstlane(blockIdx.x * 4 + w);
  if (row >= B_PAD) return;

  const int blk  = row >> 6;
  const int rloc = row & 63;
  unsigned char* base = ximg + (size_t)blk * XBLK + rloc * 256;
  const unsigned int sw  = (unsigned)(rloc & 7) << 4;
  const unsigned int off = (((unsigned)(l * 8)) & 255u) ^ sw;
  const int kcs = l >> 5;

  if (row < B_TOTAL) {
    const size_t fo = (size_t)l * 4;   // 4 bf16 per lane per row
    const int node = nodes[row];
    uint2v vs  = ld8(fb + (size_t)node * FDIM + fo);
    uint2v n0  = ld8(fb + (size_t)neigh[row * NSAMP +  0] * FDIM + fo);
    uint2v n1  = ld8(fb + (size_t)neigh[row * NSAMP +  1] * FDIM + fo);
    uint2v n2  = ld8(fb + (size_t)neigh[row * NSAMP +  2] * FDIM + fo);
    uint2v n3  = ld8(fb + (size_t)neigh[row * NSAMP +  3] * FDIM + fo);
    uint2v n4  = ld8(fb + (size_t)neigh[row * NSAMP +  4] * FDIM + fo);
    uint2v n5  = ld8(fb + (size_t)neigh[row * NSAMP +  5] * FDIM + fo);
    uint2v n6  = ld8(fb + (size_t)neigh[row * NSAMP +  6] * FDIM + fo);
    uint2v n7  = ld8(fb + (size_t)neigh[row * NSAMP +  7] * FDIM + fo);
    uint2v n8  = ld8(fb + (size_t)neigh[row * NSAMP +  8] * FDIM + fo);
    uint2v n9  = ld8(fb + (size_t)neigh[row * NSAMP +  9] * FDIM + fo);
    uint2v n10 = ld8(fb + (size_t)neigh[row * NSAMP + 10] * FDIM + fo);
    uint2v n11 = ld8(fb + (size_t)neigh[row * NSAMP + 11] * FDIM + fo);
    uint2v n12 = ld8(fb + (size_t)neigh[row * NSAMP + 12] * FDIM + fo);
    uint2v n13 = ld8(fb + (size_t)neigh[row * NSAMP + 13] * FDIM + fo);
    uint2v n14 = ld8(fb + (size_t)neigh[row * NSAMP + 14] * FDIM + fo);
    uint2v n15 = ld8(fb + (size_t)neigh[row * NSAMP + 15] * FDIM + fo);
    asm volatile("s_waitcnt vmcnt(0)" ::: "memory");
    __builtin_amdgcn_sched_barrier(0);

    float4v a0  = bf4_to_f32(n0)  + bf4_to_f32(n1);
    float4v a1  = bf4_to_f32(n2)  + bf4_to_f32(n3);
    float4v a2  = bf4_to_f32(n4)  + bf4_to_f32(n5);
    float4v a3  = bf4_to_f32(n6)  + bf4_to_f32(n7);
    float4v a4  = bf4_to_f32(n8)  + bf4_to_f32(n9);
    float4v a5  = bf4_to_f32(n10) + bf4_to_f32(n11);
    float4v a6  = bf4_to_f32(n12) + bf4_to_f32(n13);
    float4v a7  = bf4_to_f32(n14) + bf4_to_f32(n15);
    a0 += a1; a2 += a3; a4 += a5; a6 += a7;
    a0 += a2; a4 += a6;
    a0 += a4;
    a0 *= 0.0625f;

    *(uint2v*)(base + kcs * XCHUNK + off)        = vs;          // self (already bf16)
    *(short4v*)(base + (2 + kcs) * XCHUNK + off) = pack4(a0);   // mean
  } else {
    uint2v z = {0u, 0u};
    *(uint2v*)(base + kcs * XCHUNK + off)       = z;
    *(uint2v*)(base + (2 + kcs) * XCHUNK + off) = z;
  }
}

// ---------------------------------------------------------------------------
// Kernel 1-alt (ws too small for bf16 image): f32 gather, round-3 version.
// ---------------------------------------------------------------------------
__global__ __launch_bounds__(256, 4) void gather_mean(
    const int* __restrict__ nodes,
    const int* __restrict__ neigh,
    const float* __restrict__ features,
    unsigned char* __restrict__ ximg) {
  const int l = threadIdx.x & 63;
  const int w = threadIdx.x >> 6;
  const int row = __builtin_amdgcn_readfirstlane(blockIdx.x * 4 + w);
  if (row >= B_PAD) return;

  const int blk  = row >> 6;
  const int rloc = row & 63;
  unsigned char* base = ximg + (size_t)blk * XBLK + rloc * 256;
  const unsigned int sw  = (unsigned)(rloc & 7) << 4;
  const unsigned int off = (((unsigned)(l * 8)) & 255u) ^ sw;
  const int kcs = l >> 5;

  if (row < B_TOTAL) {
    const int node = nodes[row];
    const size_t fo = (size_t)l * 4;
    float4v vs = *(const float4v*)(features + (size_t)node * FDIM + fo);
    float4v accv = {0.f, 0.f, 0.f, 0.f};
    #pragma unroll
    for (int s = 0; s < NSAMP; ++s)
      accv += *(const float4v*)(features + (size_t)neigh[row * NSAMP + s] * FDIM + fo);
    accv *= 0.0625f;
    *(short4v*)(base + kcs * XCHUNK + off)       = pack4(vs);
    *(short4v*)(base + (2 + kcs) * XCHUNK + off) = pack4(accv);
  } else {
    short4v z = {0, 0, 0, 0};
    *(short4v*)(base + kcs * XCHUNK + off)       = z;
    *(short4v*)(base + (2 + kcs) * XCHUNK + off) = z;
  }
}

// ---------------------------------------------------------------------------
// Kernel 2: out[e,b] = relu( sum_k W[e,k] * X[b,k] ), MFMA bf16.
// ---------------------------------------------------------------------------
__global__ __launch_bounds__(256) void gemm_relu(
    const unsigned char* __restrict__ ximg,
    const unsigned char* __restrict__ wimg,
    float* __restrict__ out) {
  __shared__ alignas(16) unsigned char lds_w[EDIM * 256];   // 64KB
  __shared__ alignas(16) unsigned char lds_x[NBT * 256];    // 16KB

  const int tid = threadIdx.x;
  const int l   = tid & 63;
  const int w   = tid >> 6;
  const int lr  = l & 15;
  const int g   = l >> 4;
  const int b0  = blockIdx.x * NBT;
  const unsigned char* xsrc = ximg + (size_t)blockIdx.x * XBLK;

  float4v acc[4][4];
  #pragma unroll
  for (int mi = 0; mi < 4; ++mi)
    #pragma unroll
    for (int ni = 0; ni < 4; ++ni)
      acc[mi][ni] = (float4v){0.f, 0.f, 0.f, 0.f};

  for (int kc = 0; kc < 4; ++kc) {
    __syncthreads();
    {
      const unsigned char* ws_ = wimg + kc * 65536;
      #pragma unroll
      for (int i = 0; i < 16; ++i)
        lds_load16(ws_ + i * 4096 + tid * 16, lds_w + i * 4096 + (w << 10));
      const unsigned char* xs_ = xsrc + kc * XCHUNK;
      #pragma unroll
      for (int i = 0; i < 4; ++i)
        lds_load16(xs_ + i * 4096 + tid * 16, lds_x + i * 4096 + (w << 10));
    }
    __syncthreads();
    #pragma unroll
    for (int ks = 0; ks < 4; ++ks) {
      const int ko = ks * 32;
      short8v afr[4], bfr[4];
      #pragma unroll
      for (int mi = 0; mi < 4; ++mi) {
        const int e = w * 64 + mi * 16 + lr;
        const unsigned int sw = (unsigned)(e & 7) << 4;
        const unsigned char* base = lds_w + e * 256;
        short4v lo = *(const short4v*)(base + (((unsigned)((ko + 4 * g) * 2)) ^ sw));
        short4v hi = *(const short4v*)(base + (((unsigned)((ko + 16 + 4 * g) * 2)) ^ sw));
        afr[mi] = __builtin_shufflevector(lo, hi, 0, 1, 2, 3, 4, 5, 6, 7);
      }
      #pragma unroll
      for (int ni = 0; ni < 4; ++ni) {
        const int r = ni * 16 + lr;
        const unsigned int sw = (unsigned)(r & 7) << 4;
        const unsigned char* base = lds_x + r * 256;
        short4v lo = *(const short4v*)(base + (((unsigned)((ko + 4 * g) * 2)) ^ sw));
        short4v hi = *(const short4v*)(base + (((unsigned)((ko + 16 + 4 * g) * 2)) ^ sw));
        bfr[ni] = __builtin_shufflevector(lo, hi, 0, 1, 2, 3, 4, 5, 6, 7);
      }
      #pragma unroll
      for (int mi = 0; mi < 4; ++mi)
        #pragma unroll
        for (int ni = 0; ni < 4; ++ni)
          acc[mi][ni] = __builtin_amdgcn_mfma_f32_16x16x32_bf16(afr[mi], bfr[ni], acc[mi][ni], 0, 0, 0);
    }
  }

  #pragma unroll
  for (int ni = 0; ni < 4; ++ni) {
    const int b = b0 + ni * 16 + lr;
    if (b >= B_TOTAL) continue;
    #pragma unroll
    for (int mi = 0; mi < 4; ++mi) {
      const int e = w * 64 + mi * 16 + g * 4;
      #pragma unroll
      for (int q = 0; q < 4; ++q) {
        float v = acc[mi][ni][q];
        out[(size_t)(e + q) * B_TOTAL + b] = v > 0.f ? v : 0.f;
      }
    }
  }
}

// ---------------------------------------------------------------------------
// Fallback (ws tiny): round-1 fused kernel, known-correct.
// ---------------------------------------------------------------------------
__global__ __launch_bounds__(256, 1) void encoder_fused(
    const int* __restrict__ nodes,
    const int* __restrict__ neigh,
    const float* __restrict__ features,
    const float* __restrict__ weight,
    float* __restrict__ out) {
  __shared__ alignas(16) unsigned char lds_cmb[64 * KDIM * 2];
  __shared__ alignas(16) unsigned char lds_w[EDIM * 128 * 2];

  const int tid = threadIdx.x;
  const int l   = tid & 63;
  const int w   = tid >> 6;
  const int b0  = blockIdx.x * 64;

  for (int rr = 0; rr < 16; ++rr) {
    const int r  = w * 16 + rr;
    const int rb = b0 + r;
    unsigned char* rowp = lds_cmb + r * (KDIM * 2);
    const unsigned int sw = (unsigned)(r & 7) << 4;
    if (rb < B_TOTAL) {
      const int node = nodes[rb];
      float4v selfv = *(const float4v*)(features + (size_t)node * FDIM + l * 4);
      float4v accv = {0.f, 0.f, 0.f, 0.f};
      #pragma unroll
      for (int s = 0; s < NSAMP; ++s) {
        const int ni = neigh[rb * NSAMP + s];
        accv += *(const float4v*)(features + (size_t)ni * FDIM + l * 4);
      }
      accv *= 0.0625f;
      *(short4v*)(rowp + (((unsigned)(l * 8)) ^ sw))       = pack4(selfv);
      *(short4v*)(rowp + (((unsigned)(512 + l * 8)) ^ sw)) = pack4(accv);
    } else {
      short4v z = {0, 0, 0, 0};
      *(short4v*)(rowp + (((unsigned)(l * 8)) ^ sw))       = z;
      *(short4v*)(rowp + (((unsigned)(512 + l * 8)) ^ sw)) = z;
    }
  }

  const int lr = l & 15;
  const int g  = l >> 4;
  float4v acc[4][4];
  #pragma unroll
  for (int mi = 0; mi < 4; ++mi)
    #pragma unroll
    for (int ni = 0; ni < 4; ++ni)
      acc[mi][ni] = (float4v){0.f, 0.f, 0.f, 0.f};

  for (int kc = 0; kc < 4; ++kc) {
    __syncthreads();
    const int k0 = kc * 128;
    for (int i = tid; i < EDIM * 32; i += 256) {
      const int e  = i >> 5;
      const int kq = i & 31;
      float4v wv = *(const float4v*)(weight + (size_t)e * KDIM + k0 + kq * 4);
      *(short4v*)(lds_w + e * 256 + (((unsigned)(kq * 8)) ^ ((unsigned)(e & 7) << 4))) = pack4(wv);
    }
    __syncthreads();
    #pragma unroll
    for (int ks = 0; ks < 4; ++ks) {
      const int ko = ks * 32;
      short8v afr[4], bfr[4];
      #pragma unroll
      for (int mi = 0; mi < 4; ++mi) {
        const int e = w * 64 + mi * 16 + lr;
        const unsigned int sw = (unsigned)(e & 7) << 4;
        const unsigned char* base = lds_w + e * 256;
        short4v lo = *(const short4v*)(base + (((unsigned)((ko + 4 * g) * 2)) ^ sw));
        short4v hi = *(const short4v*)(base + (((unsigned)((ko + 16 + 4 * g) * 2)) ^ sw));
        afr[mi] = __builtin_shufflevector(lo, hi, 0, 1, 2, 3, 4, 5, 6, 7);
      }
      #pragma unroll
      for (int ni = 0; ni < 4; ++ni) {
        const int rrow = ni * 16 + lr;
        const unsigned int sw = (unsigned)(rrow & 7) << 4;
        const unsigned char* base = lds_cmb + rrow * (KDIM * 2);
        const int kk = k0 + ko;
        short4v lo = *(const short4v*)(base + (((unsigned)((kk + 4 * g) * 2)) ^ sw));
        short4v hi = *(const short4v*)(base + (((unsigned)((kk + 16 + 4 * g) * 2)) ^ sw));
        bfr[ni] = __builtin_shufflevector(lo, hi, 0, 1, 2, 3, 4, 5, 6, 7);
      }
      #pragma unroll
      for (int mi = 0; mi < 4; ++mi)
        #pragma unroll
        for (int ni = 0; ni < 4; ++ni)
          acc[mi][ni] = __builtin_amdgcn_mfma_f32_16x16x32_bf16(afr[mi], bfr[ni], acc[mi][ni], 0, 0, 0);
    }
  }

  #pragma unroll
  for (int ni = 0; ni < 4; ++ni) {
    const int b = b0 + ni * 16 + lr;
    if (b >= B_TOTAL) continue;
    #pragma unroll
    for (int mi = 0; mi < 4; ++mi) {
      const int e = w * 64 + mi * 16 + g * 4;
      #pragma unroll
      for (int q = 0; q < 4; ++q) {
        float v = acc[mi][ni][q];
        out[(size_t)(e + q) * B_TOTAL + b] = v > 0.f ? v : 0.f;
      }
    }
  }
}

extern "C" void kernel_launch(void* const* d_in, const int* in_sizes, int n_in,
                              void* d_out, int out_size, void* d_ws, size_t ws_size,
                              hipStream_t stream) {
  const int*   nodes    = (const int*)d_in[0];
  const int*   neigh    = (const int*)d_in[1];
  const float* features = (const float*)d_in[2];
  const float* weight   = (const float*)d_in[3];
  float*       out      = (float*)d_out;

  if (ws_size >= FB_OFF + FB_SZ) {
    unsigned char*  ximg = (unsigned char*)d_ws;
    unsigned char*  wimg = (unsigned char*)d_ws + WIMG_OFF;
    unsigned short* fb   = (unsigned short*)((unsigned char*)d_ws + FB_OFF);
    feat_pack<<<(N_NODES * FDIM / 8 + 255) / 256, 256, 0, stream>>>(features, fb);
    pack_w<<<128, 256, 0, stream>>>(weight, wimg);
    gather_mean_bf16<<<B_PAD / 4, 256, 0, stream>>>(nodes, neigh, fb, ximg);
    gemm_relu<<<NBLK, 256, 0, stream>>>(ximg, wimg, out);
  } else if (ws_size >= WIMG_OFF + WIMG_SZ) {
    unsigned char* ximg = (unsigned char*)d_ws;
    unsigned char* wimg = (unsigned char*)d_ws + WIMG_OFF;
    pack_w<<<128, 256, 0, stream>>>(weight, wimg);
    gather_mean<<<B_PAD / 4, 256, 0, stream>>>(nodes, neigh, features, ximg);
    gemm_relu<<<NBLK, 256, 0, stream>>>(ximg, wimg, out);
  } else {
    encoder_fused<<<(B_TOTAL + 63) / 64, 256, 0, stream>>>(nodes, neigh, features, weight, out);
  }
}

// Round 5
// 119.769 us; speedup vs baseline: 2.6878x; 1.0270x over previous
//
#include <hip/hip_runtime.h>

#define N_NODES 100000
#define B_TOTAL 50000
#define NSAMP   16
#define FDIM    256
#define KDIM    512   // 2*FDIM
#define EDIM    256
#define NBT     64    // batch rows per fused block
#define B_PAD   50048 // B_TOTAL rounded to NBT
#define NBLK    (B_PAD / NBT)   // 782

// ws layout (fused path): W image [kc=4][e=256][256B swizzled] = 256KB, then
// bf16 feature image [100000][256] = 51.2MB.
#define WIMG_SZ  (4 * 65536)
#define FB_OFF   ((size_t)WIMG_SZ)
#define FB_SZ    ((size_t)N_NODES * FDIM * 2)

typedef __attribute__((ext_vector_type(4))) float float4v;
typedef __attribute__((ext_vector_type(4))) short short4v;
typedef __attribute__((ext_vector_type(8))) short short8v;
typedef __attribute__((ext_vector_type(2))) unsigned int uint2v;

__device__ __forceinline__ unsigned short f2bf(float f) {
  unsigned int u = __builtin_bit_cast(unsigned int, f);
  u += 0x7FFFu + ((u >> 16) & 1u);   // round-to-nearest-even
  return (unsigned short)(u >> 16);
}

__device__ __forceinline__ short4v pack4(float4v v) {
  short4v r;
  r[0] = (short)f2bf(v[0]);
  r[1] = (short)f2bf(v[1]);
  r[2] = (short)f2bf(v[2]);
  r[3] = (short)f2bf(v[3]);
  return r;
}

__device__ __forceinline__ uint2v pack4u(float4v v) {
  unsigned int lo = ((unsigned)f2bf(v[1]) << 16) | f2bf(v[0]);
  unsigned int hi = ((unsigned)f2bf(v[3]) << 16) | f2bf(v[2]);
  uint2v r; r[0] = lo; r[1] = hi;
  return r;
}

__device__ __forceinline__ float4v bf4_to_f32(uint2v u) {
  float4v r;
  r[0] = __builtin_bit_cast(float, u[0] << 16);
  r[1] = __builtin_bit_cast(float, u[0] & 0xffff0000u);
  r[2] = __builtin_bit_cast(float, u[1] << 16);
  r[3] = __builtin_bit_cast(float, u[1] & 0xffff0000u);
  return r;
}

// Inline-asm 8B load: compiler cannot serialize these; we wait manually.
__device__ __forceinline__ uint2v ld8(const void* p) {
  uint2v r;
  asm volatile("global_load_dwordx2 %0, %1, off" : "=v"(r) : "v"(p) : "memory");
  return r;
}

__device__ __forceinline__ void lds_load16(const void* g, void* l) {
  __builtin_amdgcn_global_load_lds(
      (const __attribute__((address_space(1))) unsigned int*)g,
      (__attribute__((address_space(3))) unsigned int*)l, 16, 0, 0);
}

// ---------------------------------------------------------------------------
// Kernel A: features f32 -> bf16 linear image (one-time, 102R + 51W MB).
// ---------------------------------------------------------------------------
__global__ __launch_bounds__(256) void feat_pack(
    const float* __restrict__ f, unsigned short* __restrict__ o) {
  const size_t i = ((size_t)blockIdx.x * 256 + threadIdx.x) * 8;
  if (i >= (size_t)N_NODES * FDIM) return;
  float4v a = *(const float4v*)(f + i);
  float4v b = *(const float4v*)(f + i + 4);
  short4v ra = pack4(a), rb = pack4(b);
  short8v r;
  r[0]=ra[0]; r[1]=ra[1]; r[2]=ra[2]; r[3]=ra[3];
  r[4]=rb[0]; r[5]=rb[1]; r[6]=rb[2]; r[7]=rb[3];
  *(short8v*)(o + i) = r;
}

// ---------------------------------------------------------------------------
// Kernel 0: pack W f32 [256][512] -> bf16 swizzled image in ws.
// ---------------------------------------------------------------------------
__global__ __launch_bounds__(256) void pack_w(
    const float* __restrict__ weight, unsigned char* __restrict__ wimg) {
  const int idx = blockIdx.x * 256 + threadIdx.x;   // 32768 total
  const int e  = idx >> 7;
  const int kq = idx & 127;
  const int k  = kq * 4;
  const int kc = k >> 7;
  const int kl = k & 127;
  float4v wv = *(const float4v*)(weight + (size_t)e * KDIM + k);
  *(short4v*)(wimg + kc * 65536 + e * 256 +
              (((unsigned)(kl * 2)) ^ ((unsigned)(e & 7) << 4))) = pack4(wv);
}

// ---------------------------------------------------------------------------
// Fused kernel: gather+mean (-> registers) then MFMA GEMM + ReLU.
// 4 waves, 64 batch rows/block; LDS = 64KB W chunk + 16KB X chunk -> 2 blk/CU.
// Block i's MFMA overlaps block j's gather on the same CU.
// ---------------------------------------------------------------------------
__global__ __launch_bounds__(256, 2) void fused_gg(
    const int* __restrict__ nodes,
    const int* __restrict__ neigh,
    const unsigned short* __restrict__ fb,
    const unsigned char* __restrict__ wimg,
    float* __restrict__ out) {
  __shared__ alignas(16) unsigned char lds_w[EDIM * 256];   // 64KB
  __shared__ alignas(16) unsigned char lds_x[NBT * 256];    // 16KB per K-chunk

  const int tid = threadIdx.x;
  const int l   = tid & 63;
  const int w   = tid >> 6;     // 0..3
  const int lr  = l & 15;
  const int g   = l >> 4;
  const int b0  = blockIdx.x * NBT;

  // ---- Phase 1: gather this wave's 16 rows into registers ----
  // per row, per lane: 4 bf16 self (xs) + 4 bf16 mean (xm) -> 4 VGPRs/row.
  uint2v xs[16], xm[16];
  const int rbase = __builtin_amdgcn_readfirstlane(b0 + w * 16);
  const size_t fo = (size_t)l * 4;
  #pragma unroll
  for (int r = 0; r < 16; ++r) {
    const int rb  = rbase + r;
    const int rbc = rb < B_TOTAL ? rb : 0;
    const int node = nodes[rbc];
    uint2v vs  = ld8(fb + (size_t)node * FDIM + fo);
    uint2v n0  = ld8(fb + (size_t)neigh[rbc * NSAMP +  0] * FDIM + fo);
    uint2v n1  = ld8(fb + (size_t)neigh[rbc * NSAMP +  1] * FDIM + fo);
    uint2v n2  = ld8(fb + (size_t)neigh[rbc * NSAMP +  2] * FDIM + fo);
    uint2v n3  = ld8(fb + (size_t)neigh[rbc * NSAMP +  3] * FDIM + fo);
    uint2v n4  = ld8(fb + (size_t)neigh[rbc * NSAMP +  4] * FDIM + fo);
    uint2v n5  = ld8(fb + (size_t)neigh[rbc * NSAMP +  5] * FDIM + fo);
    uint2v n6  = ld8(fb + (size_t)neigh[rbc * NSAMP +  6] * FDIM + fo);
    uint2v n7  = ld8(fb + (size_t)neigh[rbc * NSAMP +  7] * FDIM + fo);
    uint2v n8  = ld8(fb + (size_t)neigh[rbc * NSAMP +  8] * FDIM + fo);
    uint2v n9  = ld8(fb + (size_t)neigh[rbc * NSAMP +  9] * FDIM + fo);
    uint2v n10 = ld8(fb + (size_t)neigh[rbc * NSAMP + 10] * FDIM + fo);
    uint2v n11 = ld8(fb + (size_t)neigh[rbc * NSAMP + 11] * FDIM + fo);
    uint2v n12 = ld8(fb + (size_t)neigh[rbc * NSAMP + 12] * FDIM + fo);
    uint2v n13 = ld8(fb + (size_t)neigh[rbc * NSAMP + 13] * FDIM + fo);
    uint2v n14 = ld8(fb + (size_t)neigh[rbc * NSAMP + 14] * FDIM + fo);
    uint2v n15 = ld8(fb + (size_t)neigh[rbc * NSAMP + 15] * FDIM + fo);
    asm volatile("s_waitcnt vmcnt(0)" ::: "memory");
    __builtin_amdgcn_sched_barrier(0);

    float4v a0 = bf4_to_f32(n0)  + bf4_to_f32(n1);
    float4v a1 = bf4_to_f32(n2)  + bf4_to_f32(n3);
    float4v a2 = bf4_to_f32(n4)  + bf4_to_f32(n5);
    float4v a3 = bf4_to_f32(n6)  + bf4_to_f32(n7);
    float4v a4 = bf4_to_f32(n8)  + bf4_to_f32(n9);
    float4v a5 = bf4_to_f32(n10) + bf4_to_f32(n11);
    float4v a6 = bf4_to_f32(n12) + bf4_to_f32(n13);
    float4v a7 = bf4_to_f32(n14) + bf4_to_f32(n15);
    a0 += a1; a2 += a3; a4 += a5; a6 += a7;
    a0 += a2; a4 += a6;
    a0 += a4;
    a0 *= 0.0625f;

    if (rb < B_TOTAL) {
      xs[r] = vs;
      xm[r] = pack4u(a0);
    } else {
      uint2v z = {0u, 0u};
      xs[r] = z;
      xm[r] = z;
    }
  }

  // ---- Phase 2: K-chunked MFMA GEMM ----
  float4v acc[4][4];
  #pragma unroll
  for (int mi = 0; mi < 4; ++mi)
    #pragma unroll
    for (int ni = 0; ni < 4; ++ni)
      acc[mi][ni] = (float4v){0.f, 0.f, 0.f, 0.f};

  const unsigned int xsw  = (unsigned)((w * 16) & 7) << 4;  // row&7 dep below
  (void)xsw;

  for (int kc = 0; kc < 4; ++kc) {
    __syncthreads();   // prev MFMA reads done; lds_w / lds_x reusable
    // stage W chunk: 64KB via global_load_lds
    {
      const unsigned char* ws_ = wimg + kc * 65536;
      #pragma unroll
      for (int i = 0; i < 16; ++i)
        lds_load16(ws_ + i * 4096 + tid * 16, lds_w + i * 4096 + (w << 10));
    }
    // write X chunk from registers: chunk kc<2 = self halves, kc>=2 = mean.
    {
      const bool self_sel = kc < 2;
      const int  half     = kc & 1;
      if ((l >> 5) == half) {
        const unsigned int off = (((unsigned)(l * 8)) & 255u);
        #pragma unroll
        for (int r = 0; r < 16; ++r) {
          const int rg = w * 16 + r;
          const unsigned int sw = (unsigned)(rg & 7) << 4;
          uint2v v = self_sel ? xs[r] : xm[r];
          *(uint2v*)(lds_x + rg * 256 + (off ^ sw)) = v;
        }
      }
    }
    __syncthreads();
    #pragma unroll
    for (int ks = 0; ks < 4; ++ks) {
      const int ko = ks * 32;
      short8v afr[4], bfr[4];
      #pragma unroll
      for (int mi = 0; mi < 4; ++mi) {
        const int e = w * 64 + mi * 16 + lr;
        const unsigned int sw = (unsigned)(e & 7) << 4;
        const unsigned char* base = lds_w + e * 256;
        short4v lo = *(const short4v*)(base + (((unsigned)((ko + 4 * g) * 2)) ^ sw));
        short4v hi = *(const short4v*)(base + (((unsigned)((ko + 16 + 4 * g) * 2)) ^ sw));
        afr[mi] = __builtin_shufflevector(lo, hi, 0, 1, 2, 3, 4, 5, 6, 7);
      }
      #pragma unroll
      for (int ni = 0; ni < 4; ++ni) {
        const int r = ni * 16 + lr;
        const unsigned int sw = (unsigned)(r & 7) << 4;
        const unsigned char* base = lds_x + r * 256;
        short4v lo = *(const short4v*)(base + (((unsigned)((ko + 4 * g) * 2)) ^ sw));
        short4v hi = *(const short4v*)(base + (((unsigned)((ko + 16 + 4 * g) * 2)) ^ sw));
        bfr[ni] = __builtin_shufflevector(lo, hi, 0, 1, 2, 3, 4, 5, 6, 7);
      }
      #pragma unroll
      for (int mi = 0; mi < 4; ++mi)
        #pragma unroll
        for (int ni = 0; ni < 4; ++ni)
          acc[mi][ni] = __builtin_amdgcn_mfma_f32_16x16x32_bf16(afr[mi], bfr[ni], acc[mi][ni], 0, 0, 0);
    }
  }

  // ---- Epilogue: ReLU + store ----
  #pragma unroll
  for (int ni = 0; ni < 4; ++ni) {
    const int b = b0 + ni * 16 + lr;
    if (b >= B_TOTAL) continue;
    #pragma unroll
    for (int mi = 0; mi < 4; ++mi) {
      const int e = w * 64 + mi * 16 + g * 4;
      #pragma unroll
      for (int q = 0; q < 4; ++q) {
        float v = acc[mi][ni][q];
        out[(size_t)(e + q) * B_TOTAL + b] = v > 0.f ? v : 0.f;
      }
    }
  }
}

// ---------------------------------------------------------------------------
// Fallback (ws too small): round-1 fused kernel, known-correct.
// ---------------------------------------------------------------------------
__global__ __launch_bounds__(256, 1) void encoder_fused(
    const int* __restrict__ nodes,
    const int* __restrict__ neigh,
    const float* __restrict__ features,
    const float* __restrict__ weight,
    float* __restrict__ out) {
  __shared__ alignas(16) unsigned char lds_cmb[64 * KDIM * 2];
  __shared__ alignas(16) unsigned char lds_w[EDIM * 128 * 2];

  const int tid = threadIdx.x;
  const int l   = tid & 63;
  const int w   = tid >> 6;
  const int b0  = blockIdx.x * 64;

  for (int rr = 0; rr < 16; ++rr) {
    const int r  = w * 16 + rr;
    const int rb = b0 + r;
    unsigned char* rowp = lds_cmb + r * (KDIM * 2);
    const unsigned int sw = (unsigned)(r & 7) << 4;
    if (rb < B_TOTAL) {
      const int node = nodes[rb];
      float4v selfv = *(const float4v*)(features + (size_t)node * FDIM + l * 4);
      float4v accv = {0.f, 0.f, 0.f, 0.f};
      #pragma unroll
      for (int s = 0; s < NSAMP; ++s) {
        const int ni = neigh[rb * NSAMP + s];
        accv += *(const float4v*)(features + (size_t)ni * FDIM + l * 4);
      }
      accv *= 0.0625f;
      *(short4v*)(rowp + (((unsigned)(l * 8)) ^ sw))       = pack4(selfv);
      *(short4v*)(rowp + (((unsigned)(512 + l * 8)) ^ sw)) = pack4(accv);
    } else {
      short4v z = {0, 0, 0, 0};
      *(short4v*)(rowp + (((unsigned)(l * 8)) ^ sw))       = z;
      *(short4v*)(rowp + (((unsigned)(512 + l * 8)) ^ sw)) = z;
    }
  }

  const int lr = l & 15;
  const int g  = l >> 4;
  float4v acc[4][4];
  #pragma unroll
  for (int mi = 0; mi < 4; ++mi)
    #pragma unroll
    for (int ni = 0; ni < 4; ++ni)
      acc[mi][ni] = (float4v){0.f, 0.f, 0.f, 0.f};

  for (int kc = 0; kc < 4; ++kc) {
    __syncthreads();
    const int k0 = kc * 128;
    for (int i = tid; i < EDIM * 32; i += 256) {
      const int e  = i >> 5;
      const int kq = i & 31;
      float4v wv = *(const float4v*)(weight + (size_t)e * KDIM + k0 + kq * 4);
      *(short4v*)(lds_w + e * 256 + (((unsigned)(kq * 8)) ^ ((unsigned)(e & 7) << 4))) = pack4(wv);
    }
    __syncthreads();
    #pragma unroll
    for (int ks = 0; ks < 4; ++ks) {
      const int ko = ks * 32;
      short8v afr[4], bfr[4];
      #pragma unroll
      for (int mi = 0; mi < 4; ++mi) {
        const int e = w * 64 + mi * 16 + lr;
        const unsigned int sw = (unsigned)(e & 7) << 4;
        const unsigned char* base = lds_w + e * 256;
        short4v lo = *(const short4v*)(base + (((unsigned)((ko + 4 * g) * 2)) ^ sw));
        short4v hi = *(const short4v*)(base + (((unsigned)((ko + 16 + 4 * g) * 2)) ^ sw));
        afr[mi] = __builtin_shufflevector(lo, hi, 0, 1, 2, 3, 4, 5, 6, 7);
      }
      #pragma unroll
      for (int ni = 0; ni < 4; ++ni) {
        const int rrow = ni * 16 + lr;
        const unsigned int sw = (unsigned)(rrow & 7) << 4;
        const unsigned char* base = lds_cmb + rrow * (KDIM * 2);
        const int kk = k0 + ko;
        short4v lo = *(const short4v*)(base + (((unsigned)((kk + 4 * g) * 2)) ^ sw));
        short4v hi = *(const short4v*)(base + (((unsigned)((kk + 16 + 4 * g) * 2)) ^ sw));
        bfr[ni] = __builtin_shufflevector(lo, hi, 0, 1, 2, 3, 4, 5, 6, 7);
      }
      #pragma unroll
      for (int mi = 0; mi < 4; ++mi)
        #pragma unroll
        for (int ni = 0; ni < 4; ++ni)
          acc[mi][ni] = __builtin_amdgcn_mfma_f32_16x16x32_bf16(afr[mi], bfr[ni], acc[mi][ni], 0, 0, 0);
    }
  }

  #pragma unroll
  for (int ni = 0; ni < 4; ++ni) {
    const int b = b0 + ni * 16 + lr;
    if (b >= B_TOTAL) continue;
    #pragma unroll
    for (int mi = 0; mi < 4; ++mi) {
      const int e = w * 64 + mi * 16 + g * 4;
      #pragma unroll
      for (int q = 0; q < 4; ++q) {
        float v = acc[mi][ni][q];
        out[(size_t)(e + q) * B_TOTAL + b] = v > 0.f ? v : 0.f;
      }
    }
  }
}

extern "C" void kernel_launch(void* const* d_in, const int* in_sizes, int n_in,
                              void* d_out, int out_size, void* d_ws, size_t ws_size,
                              hipStream_t stream) {
  const int*   nodes    = (const int*)d_in[0];
  const int*   neigh    = (const int*)d_in[1];
  const float* features = (const float*)d_in[2];
  const float* weight   = (const float*)d_in[3];
  float*       out      = (float*)d_out;

  if (ws_size >= FB_OFF + FB_SZ) {
    unsigned char*  wimg = (unsigned char*)d_ws;
    unsigned short* fb   = (unsigned short*)((unsigned char*)d_ws + FB_OFF);
    feat_pack<<<(N_NODES * FDIM / 8 + 255) / 256, 256, 0, stream>>>(features, fb);
    pack_w<<<128, 256, 0, stream>>>(weight, wimg);
    fused_gg<<<NBLK, 256, 0, stream>>>(nodes, neigh, fb, wimg, out);
  } else {
    encoder_fused<<<(B_TOTAL + 63) / 64, 256, 0, stream>>>(nodes, neigh, features, weight, out);
  }
}